// Round 9
// baseline (222.521 us; speedup 1.0000x reference)
//
#include <hip/hip_runtime.h>
#include <stdint.h>

#define Hdim 112
#define Wdim 112
#define CIN  128
#define COUT 128
#define NB   32
#define HW   (Hdim*Wdim)   // 12544

// ws layout:
//   Wi8 : int8 [9][COUT][CIN]  @ 0        (147456 B)  weight signs as +-1
//   pkx : uint4[NB*HW]         @ 147456   (6.4 MB)    packed activation sign bits

typedef int v4i  __attribute__((ext_vector_type(4)));
typedef int v16i __attribute__((ext_vector_type(16)));

__global__ void pack_w_i8(const float* __restrict__ W, char* __restrict__ Wi8) {
    int t = blockIdx.x * blockDim.x + threadIdx.x;
    if (t >= COUT * 9) return;
    int co = t / 9, tap = t % 9;
    const float* wp = W + (size_t)co * CIN * 9 + tap;
    uint32_t* dst = (uint32_t*)(Wi8 + ((size_t)tap * COUT + co) * CIN);
    #pragma unroll
    for (int c4 = 0; c4 < 32; c4++) {
        uint32_t word = 0;
        #pragma unroll
        for (int j = 0; j < 4; j++) {
            uint32_t neg = __float_as_uint(wp[(size_t)(c4 * 4 + j) * 9]) >> 31;
            word |= (neg ? 0xFFu : 0x01u) << (8 * j);
        }
        dst[c4] = word;
    }
}

// each thread packs 4 consecutive pixels across all 128 channels (float4 loads)
__global__ __launch_bounds__(256) void pack_x_kernel(const float* __restrict__ x,
                                                     uint4* __restrict__ pkx) {
    int gid = blockIdx.x * blockDim.x + threadIdx.x;   // 0..100351
    int n = gid / (HW / 4);
    int p = (gid - n * (HW / 4)) * 4;
    const float* xp = x + (size_t)n * CIN * HW + p;
    uint32_t m[4][4] = {{0,0,0,0},{0,0,0,0},{0,0,0,0},{0,0,0,0}};
    #pragma unroll
    for (int c = 0; c < CIN; c++) {
        float4 v = *reinterpret_cast<const float4*>(xp + (size_t)c * HW);
        int q = c >> 5, s = c & 31;
        m[0][q] |= (__float_as_uint(v.x) >> 31) << s;
        m[1][q] |= (__float_as_uint(v.y) >> 31) << s;
        m[2][q] |= (__float_as_uint(v.z) >> 31) << s;
        m[3][q] |= (__float_as_uint(v.w) >> 31) << s;
    }
    uint4* op = pkx + (size_t)n * HW + p;
    #pragma unroll
    for (int j = 0; j < 4; j++)
        op[j] = make_uint4(m[j][0], m[j][1], m[j][2], m[j][3]);
}

// spread low 4 bits into 4 bytes: bit=0 -> 0x01 (+1), bit=1 -> 0xFF (-1)
__device__ __forceinline__ uint32_t expand4(uint32_t b) {
    uint32_t s = ((b & 0xFu) * 0x00204081u) & 0x01010101u;
    return 0x01010101u ^ (s * 0xFEu);
}

// implicit-GEMM binconv via i8 MFMA.
// Block: 128 co x (16w x 8h = 128 px), 4 waves, each 64co x 64px:
// acc = 2ct x 2pt x v16i = 64 AGPR, full next-tap A prefetch (32 VGPR),
// __launch_bounds__(256,3) -> ~170-reg cap, 3 waves/SIMD resident so
// prologue/epilogue/L2-latency overlap across waves (R8's (256,2) had
// only 2 and was latency-bound at ~115us vs the 33us store floor).
// Halo 10x18 px in LDS as [slot][pixel][16B]: lane-consecutive reads,
// conflict-free. OOB pixels stage as true i8 zeros -> padding exact.
__global__ __launch_bounds__(256, 3) void binconv_mfma(
    const uint4* __restrict__ pkx, const char* __restrict__ Wi8,
    const float* __restrict__ bias, float* __restrict__ out) {
    __shared__ uint4 halo4[8 * 180];        // 8 slots * 180 px * 16B = 23040 B
    char* halo = (char*)halo4;

    int tid = threadIdx.x;
    int w0 = blockIdx.x * 16;
    int h0 = blockIdx.y * 8;
    int n  = blockIdx.z;

    // stage 10x18 halo: expand 128 sign bits -> 128 i8 (+-1, 0 if OOB)
    if (tid < 180) {
        int r = tid / 18, c = tid - r * 18;
        int h = h0 - 1 + r, w = w0 - 1 + c;
        bool valid = (h >= 0) && (h < Hdim) && (w >= 0) && (w < Wdim);
        uint32_t keep = valid ? 0xFFFFFFFFu : 0u;
        uint4 bits = make_uint4(0u, 0u, 0u, 0u);
        if (valid) bits = pkx[(size_t)n * HW + h * Wdim + w];
        uint32_t src[4] = {bits.x, bits.y, bits.z, bits.w};
        #pragma unroll
        for (int s = 0; s < 8; s++) {       // slot s = ci 16s..16s+15
            uint32_t q = src[s >> 1] >> ((s & 1) * 16);
            uint4 ov;
            ov.x = expand4(q)       & keep;
            ov.y = expand4(q >> 4)  & keep;
            ov.z = expand4(q >> 8)  & keep;
            ov.w = expand4(q >> 12) & keep;
            *reinterpret_cast<uint4*>(&halo[s * 2880 + tid * 16]) = ov;
        }
    }
    __syncthreads();

    int wid = tid >> 6, l = tid & 63;
    int al = l & 31, ah = l >> 5;
    int cobase = (wid & 1) * 64;            // wave's 64-co half
    int pxbase = (wid >> 1) * 64;           // wave's 64-px half

    // per-px-tile halo byte base at tap (0,0)
    int pib[2];
    #pragma unroll
    for (int pt = 0; pt < 2; pt++) {
        int p = pxbase + pt * 32 + al;
        pib[pt] = ((p >> 4) * 18 + (p & 15)) * 16;
    }

    const char* wA = Wi8 + (size_t)(cobase + al) * CIN + ah * 16;

    v16i acc[2][2];
    #pragma unroll
    for (int ct = 0; ct < 2; ct++)
        #pragma unroll
        for (int pt = 0; pt < 2; pt++)
            #pragma unroll
            for (int i = 0; i < 16; i++) acc[ct][pt][i] = 0;

    // A fragments for tap 0 (ct=0: co+0, ct=1: co+32)
    v4i A[2][4];
    #pragma unroll
    for (int kk = 0; kk < 4; kk++) {
        A[0][kk] = *reinterpret_cast<const v4i*>(wA + kk * 32);
        A[1][kk] = *reinterpret_cast<const v4i*>(wA + 32 * CIN + kk * 32);
    }

    #pragma unroll
    for (int tap = 0; tap < 9; tap++) {
        // prefetch next tap's A while this tap's MFMAs run
        v4i N[2][4];
        if (tap < 8) {
            const char* wt = wA + (size_t)(tap + 1) * COUT * CIN;
            #pragma unroll
            for (int kk = 0; kk < 4; kk++) {
                N[0][kk] = *reinterpret_cast<const v4i*>(wt + kk * 32);
                N[1][kk] = *reinterpret_cast<const v4i*>(wt + 32 * CIN + kk * 32);
            }
        }
        int doff = ((tap / 3) * 18 + (tap % 3)) * 16;
        #pragma unroll
        for (int kk = 0; kk < 4; kk++) {
            int sb = (kk * 2 + ah) * 2880 + doff;
            v4i b0 = *reinterpret_cast<const v4i*>(&halo[sb + pib[0]]);
            v4i b1 = *reinterpret_cast<const v4i*>(&halo[sb + pib[1]]);
            acc[0][0] = __builtin_amdgcn_mfma_i32_32x32x32_i8(A[0][kk], b0, acc[0][0], 0, 0, 0);
            acc[0][1] = __builtin_amdgcn_mfma_i32_32x32x32_i8(A[0][kk], b1, acc[0][1], 0, 0, 0);
            acc[1][0] = __builtin_amdgcn_mfma_i32_32x32x32_i8(A[1][kk], b0, acc[1][0], 0, 0, 0);
            acc[1][1] = __builtin_amdgcn_mfma_i32_32x32x32_i8(A[1][kk], b1, acc[1][1], 0, 0, 0);
        }
        if (tap < 8) {
            #pragma unroll
            for (int kk = 0; kk < 4; kk++) { A[0][kk] = N[0][kk]; A[1][kk] = N[1][kk]; }
        }
    }

    // epilogue: C layout col=lane&31 (pixel), row=(reg&3)+8*(reg>>2)+4*ah (co)
    float* ob = out + (size_t)n * COUT * HW;
    #pragma unroll
    for (int ct = 0; ct < 2; ct++) {
        #pragma unroll
        for (int reg = 0; reg < 16; reg++) {
            int co = cobase + ct * 32 + (reg & 3) + ((reg >> 2) << 3) + (ah << 2);
            float bv = bias[co];
            #pragma unroll
            for (int pt = 0; pt < 2; pt++) {
                int p = pxbase + pt * 32 + al;
                int off = (h0 + (p >> 4)) * Wdim + w0 + (p & 15);
                ob[(size_t)co * HW + off] = (float)acc[ct][pt][reg] + bv;
            }
        }
    }
}

extern "C" void kernel_launch(void* const* d_in, const int* in_sizes, int n_in,
                              void* d_out, int out_size, void* d_ws, size_t ws_size,
                              hipStream_t stream) {
    const float* x = (const float*)d_in[0];
    const float* W = (const float*)d_in[1];
    const float* b = (const float*)d_in[2];
    float* out = (float*)d_out;
    char* ws = (char*)d_ws;
    char*  Wi8 = ws;
    uint4* pkx = (uint4*)(ws + 147456);

    pack_w_i8<<<dim3((COUT * 9 + 255) / 256), dim3(256), 0, stream>>>(W, Wi8);
    pack_x_kernel<<<dim3(NB * HW / 4 / 256), dim3(256), 0, stream>>>(x, pkx);
    binconv_mfma<<<dim3(7, 14, NB), dim3(256), 0, stream>>>(pkx, Wi8, b, out);
}

// Round 10
// 183.266 us; speedup vs baseline: 1.2142x; 1.2142x over previous
//
#include <hip/hip_runtime.h>
#include <stdint.h>

#define Hdim 112
#define Wdim 112
#define CIN  128
#define COUT 128
#define NB   32
#define HW   (Hdim*Wdim)   // 12544

// ws layout:
//   Wi8 : int8 [9][COUT][CIN]  @ 0        (147456 B)  weight signs as +-1
//   pkx : uint4[NB*HW]         @ 147456   (6.4 MB)    packed activation sign bits

typedef int v4i  __attribute__((ext_vector_type(4)));
typedef int v16i __attribute__((ext_vector_type(16)));

__global__ void pack_w_i8(const float* __restrict__ W, char* __restrict__ Wi8) {
    int t = blockIdx.x * blockDim.x + threadIdx.x;
    if (t >= COUT * 9) return;
    int co = t / 9, tap = t % 9;
    const float* wp = W + (size_t)co * CIN * 9 + tap;
    uint32_t* dst = (uint32_t*)(Wi8 + ((size_t)tap * COUT + co) * CIN);
    #pragma unroll
    for (int c4 = 0; c4 < 32; c4++) {
        uint32_t word = 0;
        #pragma unroll
        for (int j = 0; j < 4; j++) {
            uint32_t neg = __float_as_uint(wp[(size_t)(c4 * 4 + j) * 9]) >> 31;
            word |= (neg ? 0xFFu : 0x01u) << (8 * j);
        }
        dst[c4] = word;
    }
}

// each thread packs 4 consecutive pixels across all 128 channels (float4 loads)
__global__ __launch_bounds__(256) void pack_x_kernel(const float* __restrict__ x,
                                                     uint4* __restrict__ pkx) {
    int gid = blockIdx.x * blockDim.x + threadIdx.x;   // 0..100351
    int n = gid / (HW / 4);
    int p = (gid - n * (HW / 4)) * 4;
    const float* xp = x + (size_t)n * CIN * HW + p;
    uint32_t m[4][4] = {{0,0,0,0},{0,0,0,0},{0,0,0,0},{0,0,0,0}};
    #pragma unroll
    for (int c = 0; c < CIN; c++) {
        float4 v = *reinterpret_cast<const float4*>(xp + (size_t)c * HW);
        int q = c >> 5, s = c & 31;
        m[0][q] |= (__float_as_uint(v.x) >> 31) << s;
        m[1][q] |= (__float_as_uint(v.y) >> 31) << s;
        m[2][q] |= (__float_as_uint(v.z) >> 31) << s;
        m[3][q] |= (__float_as_uint(v.w) >> 31) << s;
    }
    uint4* op = pkx + (size_t)n * HW + p;
    #pragma unroll
    for (int j = 0; j < 4; j++)
        op[j] = make_uint4(m[j][0], m[j][1], m[j][2], m[j][3]);
}

// spread low 4 bits into 4 bytes: bit=0 -> 0x01 (+1), bit=1 -> 0xFF (-1)
__device__ __forceinline__ uint32_t expand4(uint32_t b) {
    uint32_t s = ((b & 0xFu) * 0x00204081u) & 0x01010101u;
    return 0x01010101u ^ (s * 0xFEu);
}

// implicit-GEMM binconv via i8 MFMA, all-tap weights resident in VGPRs.
// Block: 128 co x (16w x 8h = 128 px), 4 waves; wave = 32 co x 128 px.
// Per wave: Wreg[9][4] (36 x b128 = 144 VGPR, static indices only) loaded
// ONCE per block; inner loop is pure ds_read_b128 + MFMA (zero global ops,
// zero vmcnt waits — R7-R9's latency binding was the per-tap L2 A-fetch).
// acc = 4 x v16i = 64 AGPR. Block iterates 2 h-tiles to amortize the
// weight prologue. Halo [slot][pixel][16B] in LDS; OOB pixels staged as
// true i8 zeros -> zero padding exact (absmax 0.0 in R7-R9).
__global__ __launch_bounds__(256, 2) void binconv_mfma(
    const uint4* __restrict__ pkx, const char* __restrict__ Wi8,
    const float* __restrict__ bias, float* __restrict__ out) {
    __shared__ uint4 halo4[8 * 180];        // 8 slots * 180 px * 16B = 23040 B
    char* halo = (char*)halo4;

    int tid = threadIdx.x;
    int w0 = blockIdx.x * 16;
    int hy = blockIdx.y;                    // h-pair index: tiles at hy*16, hy*16+8
    int n  = blockIdx.z;

    int wid = tid >> 6, l = tid & 63;
    int al = l & 31, ah = l >> 5;
    int cobase = wid * 32;                  // wave's 32-co slice

    // ---- prologue: this wave's full 9-tap weight panel -> 144 VGPRs ----
    const char* wA = Wi8 + ((size_t)cobase + al) * CIN + ah * 16;
    v4i Wreg[9][4];
    #pragma unroll
    for (int tap = 0; tap < 9; tap++)
        #pragma unroll
        for (int kk = 0; kk < 4; kk++)
            Wreg[tap][kk] = *reinterpret_cast<const v4i*>(
                wA + (size_t)tap * COUT * CIN + kk * 32);

    // per-px-tile halo byte base at tap (0,0): px p = pt*32+al, tile 16w x 8h
    int pib[4];
    #pragma unroll
    for (int pt = 0; pt < 4; pt++) {
        int p = pt * 32 + al;
        pib[pt] = ((p >> 4) * 18 + (p & 15)) * 16;
    }

    for (int it = 0; it < 2; it++) {
        int h0 = hy * 16 + it * 8;
        if (it > 0) __syncthreads();        // prev compute done before restage

        // stage 10x18 halo: expand 128 sign bits -> 128 i8 (+-1, 0 if OOB)
        if (tid < 180) {
            int r = tid / 18, c = tid - r * 18;
            int h = h0 - 1 + r, w = w0 - 1 + c;
            bool valid = (h >= 0) && (h < Hdim) && (w >= 0) && (w < Wdim);
            uint32_t keep = valid ? 0xFFFFFFFFu : 0u;
            uint4 bits = make_uint4(0u, 0u, 0u, 0u);
            if (valid) bits = pkx[(size_t)n * HW + h * Wdim + w];
            uint32_t src[4] = {bits.x, bits.y, bits.z, bits.w};
            #pragma unroll
            for (int s = 0; s < 8; s++) {   // slot s = ci 16s..16s+15
                uint32_t q = src[s >> 1] >> ((s & 1) * 16);
                uint4 ov;
                ov.x = expand4(q)       & keep;
                ov.y = expand4(q >> 4)  & keep;
                ov.z = expand4(q >> 8)  & keep;
                ov.w = expand4(q >> 12) & keep;
                *reinterpret_cast<uint4*>(&halo[s * 2880 + tid * 16]) = ov;
            }
        }
        __syncthreads();

        v16i acc[4];
        #pragma unroll
        for (int pt = 0; pt < 4; pt++)
            #pragma unroll
            for (int i = 0; i < 16; i++) acc[pt][i] = 0;

        #pragma unroll
        for (int tap = 0; tap < 9; tap++) {
            int doff = ((tap / 3) * 18 + (tap % 3)) * 16;
            #pragma unroll
            for (int kk = 0; kk < 4; kk++) {
                int sb = (kk * 2 + ah) * 2880 + doff;
                #pragma unroll
                for (int pt = 0; pt < 4; pt++) {
                    v4i b = *reinterpret_cast<const v4i*>(&halo[sb + pib[pt]]);
                    acc[pt] = __builtin_amdgcn_mfma_i32_32x32x32_i8(
                        Wreg[tap][kk], b, acc[pt], 0, 0, 0);
                }
            }
        }

        // epilogue: C layout col=lane&31 (pixel), row=(reg&3)+8*(reg>>2)+4*ah (co)
        float* ob = out + (size_t)n * COUT * HW;
        #pragma unroll
        for (int reg = 0; reg < 16; reg++) {
            int co = cobase + (reg & 3) + ((reg >> 2) << 3) + (ah << 2);
            float bv = bias[co];
            #pragma unroll
            for (int pt = 0; pt < 4; pt++) {
                int p = pt * 32 + al;
                int off = (h0 + (p >> 4)) * Wdim + w0 + (p & 15);
                ob[(size_t)co * HW + off] = (float)acc[pt][reg] + bv;
            }
        }
    }
}

extern "C" void kernel_launch(void* const* d_in, const int* in_sizes, int n_in,
                              void* d_out, int out_size, void* d_ws, size_t ws_size,
                              hipStream_t stream) {
    const float* x = (const float*)d_in[0];
    const float* W = (const float*)d_in[1];
    const float* b = (const float*)d_in[2];
    float* out = (float*)d_out;
    char* ws = (char*)d_ws;
    char*  Wi8 = ws;
    uint4* pkx = (uint4*)(ws + 147456);

    pack_w_i8<<<dim3((COUT * 9 + 255) / 256), dim3(256), 0, stream>>>(W, Wi8);
    pack_x_kernel<<<dim3(NB * HW / 4 / 256), dim3(256), 0, stream>>>(x, pkx);
    binconv_mfma<<<dim3(7, 7, NB), dim3(256), 0, stream>>>(pkx, Wi8, b, out);
}

// Round 11
// 161.664 us; speedup vs baseline: 1.3764x; 1.1336x over previous
//
#include <hip/hip_runtime.h>
#include <stdint.h>

#define Hdim 112
#define Wdim 112
#define CIN  128
#define COUT 128
#define NB   32
#define HW   (Hdim*Wdim)   // 12544

// ws layout:
//   Wi8 : int8 [9][COUT][CIN]  @ 0        (147456 B)  weight signs as +-1
//   pkx : uint4[NB*HW]         @ 147456   (6.4 MB)    packed activation sign bits

typedef int v4i  __attribute__((ext_vector_type(4)));
typedef int v16i __attribute__((ext_vector_type(16)));

__global__ void pack_w_i8(const float* __restrict__ W, char* __restrict__ Wi8) {
    int t = blockIdx.x * blockDim.x + threadIdx.x;
    if (t >= COUT * 9) return;
    int co = t / 9, tap = t % 9;
    const float* wp = W + (size_t)co * CIN * 9 + tap;
    uint32_t* dst = (uint32_t*)(Wi8 + ((size_t)tap * COUT + co) * CIN);
    #pragma unroll
    for (int c4 = 0; c4 < 32; c4++) {
        uint32_t word = 0;
        #pragma unroll
        for (int j = 0; j < 4; j++) {
            uint32_t neg = __float_as_uint(wp[(size_t)(c4 * 4 + j) * 9]) >> 31;
            word |= (neg ? 0xFFu : 0x01u) << (8 * j);
        }
        dst[c4] = word;
    }
}

// each thread packs 4 consecutive pixels across all 128 channels (float4 loads)
__global__ __launch_bounds__(256) void pack_x_kernel(const float* __restrict__ x,
                                                     uint4* __restrict__ pkx) {
    int gid = blockIdx.x * blockDim.x + threadIdx.x;   // 0..100351
    int n = gid / (HW / 4);
    int p = (gid - n * (HW / 4)) * 4;
    const float* xp = x + (size_t)n * CIN * HW + p;
    uint32_t m[4][4] = {{0,0,0,0},{0,0,0,0},{0,0,0,0},{0,0,0,0}};
    #pragma unroll
    for (int c = 0; c < CIN; c++) {
        float4 v = *reinterpret_cast<const float4*>(xp + (size_t)c * HW);
        int q = c >> 5, s = c & 31;
        m[0][q] |= (__float_as_uint(v.x) >> 31) << s;
        m[1][q] |= (__float_as_uint(v.y) >> 31) << s;
        m[2][q] |= (__float_as_uint(v.z) >> 31) << s;
        m[3][q] |= (__float_as_uint(v.w) >> 31) << s;
    }
    uint4* op = pkx + (size_t)n * HW + p;
    #pragma unroll
    for (int j = 0; j < 4; j++)
        op[j] = make_uint4(m[j][0], m[j][1], m[j][2], m[j][3]);
}

// spread low 4 bits into 4 bytes: bit=0 -> 0x01 (+1), bit=1 -> 0xFF (-1)
__device__ __forceinline__ uint32_t expand4(uint32_t b) {
    uint32_t s = ((b & 0xFu) * 0x00204081u) & 0x01010101u;
    return 0x01010101u ^ (s * 0xFEu);
}

// implicit-GEMM binconv via i8 MFMA.
// Block: 128 co x (16w x 16h = 256 px), 4 waves; wave = 64co x 128px.
// acc = 2ct x 4pt x v16i = 128 AGPR (lives in the acc half of the unified
// file — R7-R10 showed the allocator caps ARCH VGPRs at ~128, so all
// long-lived bulk state must be AGPR/LDS). Weights: per-tap prefetch
// A[2][4]+N[2][4] = 64 transient arch regs (R8's proven footprint).
// Per tap: 8 L2 A-loads + 16 ds_read -> 32 MFMA (0.5 LDS rd/MFMA).
// Halo 18x18 px in LDS as [slot][pixel][16B]; OOB staged as true i8
// zeros -> zero padding exact (absmax 0.0 since R7).
__global__ __launch_bounds__(256, 2) void binconv_mfma(
    const uint4* __restrict__ pkx, const char* __restrict__ Wi8,
    const float* __restrict__ bias, float* __restrict__ out) {
    __shared__ uint4 halo4[8 * 324];        // 8 slots * 324 px * 16B = 41472 B
    char* halo = (char*)halo4;

    int tid = threadIdx.x;
    int w0 = blockIdx.x * 16;
    int h0 = blockIdx.y * 16;
    int n  = blockIdx.z;

    // stage 18x18 halo: expand 128 sign bits -> 128 i8 (+-1, 0 if OOB)
    for (int i = tid; i < 324; i += 256) {
        int r = i / 18, c = i - r * 18;
        int h = h0 - 1 + r, w = w0 - 1 + c;
        bool valid = (h >= 0) && (h < Hdim) && (w >= 0) && (w < Wdim);
        uint32_t keep = valid ? 0xFFFFFFFFu : 0u;
        uint4 bits = make_uint4(0u, 0u, 0u, 0u);
        if (valid) bits = pkx[(size_t)n * HW + h * Wdim + w];
        uint32_t src[4] = {bits.x, bits.y, bits.z, bits.w};
        #pragma unroll
        for (int s = 0; s < 8; s++) {       // slot s = ci 16s..16s+15
            uint32_t q = src[s >> 1] >> ((s & 1) * 16);
            uint4 ov;
            ov.x = expand4(q)       & keep;
            ov.y = expand4(q >> 4)  & keep;
            ov.z = expand4(q >> 8)  & keep;
            ov.w = expand4(q >> 12) & keep;
            *reinterpret_cast<uint4*>(&halo[s * 5184 + i * 16]) = ov;
        }
    }

    int wid = tid >> 6, l = tid & 63;
    int al = l & 31, ah = l >> 5;
    int cobase = (wid & 1) * 64;            // wave's 64-co half
    int pxbase = (wid >> 1) * 128;          // wave's 128-px half

    // per-px-tile halo byte base at tap (0,0)
    int pib[4];
    #pragma unroll
    for (int pt = 0; pt < 4; pt++) {
        int p = pxbase + pt * 32 + al;
        pib[pt] = ((p >> 4) * 18 + (p & 15)) * 16;
    }

    const char* wA = Wi8 + ((size_t)cobase + al) * CIN + ah * 16;

    // A fragments for tap 0 (ct=0: co+0, ct=1: co+32)
    v4i A[2][4];
    #pragma unroll
    for (int kk = 0; kk < 4; kk++) {
        A[0][kk] = *reinterpret_cast<const v4i*>(wA + kk * 32);
        A[1][kk] = *reinterpret_cast<const v4i*>(wA + 32 * CIN + kk * 32);
    }

    v16i acc[2][4];
    #pragma unroll
    for (int ct = 0; ct < 2; ct++)
        #pragma unroll
        for (int pt = 0; pt < 4; pt++)
            #pragma unroll
            for (int i = 0; i < 16; i++) acc[ct][pt][i] = 0;

    __syncthreads();

    #pragma unroll
    for (int tap = 0; tap < 9; tap++) {
        // prefetch next tap's A while this tap's MFMAs run
        v4i N[2][4];
        if (tap < 8) {
            const char* wt = wA + (size_t)(tap + 1) * COUT * CIN;
            #pragma unroll
            for (int kk = 0; kk < 4; kk++) {
                N[0][kk] = *reinterpret_cast<const v4i*>(wt + kk * 32);
                N[1][kk] = *reinterpret_cast<const v4i*>(wt + 32 * CIN + kk * 32);
            }
        }
        int doff = ((tap / 3) * 18 + (tap % 3)) * 16;
        #pragma unroll
        for (int kk = 0; kk < 4; kk++) {
            int sb = (kk * 2 + ah) * 5184 + doff;
            v4i b[4];
            #pragma unroll
            for (int pt = 0; pt < 4; pt++)
                b[pt] = *reinterpret_cast<const v4i*>(&halo[sb + pib[pt]]);
            #pragma unroll
            for (int pt = 0; pt < 4; pt++) {
                acc[0][pt] = __builtin_amdgcn_mfma_i32_32x32x32_i8(A[0][kk], b[pt], acc[0][pt], 0, 0, 0);
                acc[1][pt] = __builtin_amdgcn_mfma_i32_32x32x32_i8(A[1][kk], b[pt], acc[1][pt], 0, 0, 0);
            }
        }
        if (tap < 8) {
            #pragma unroll
            for (int kk = 0; kk < 4; kk++) { A[0][kk] = N[0][kk]; A[1][kk] = N[1][kk]; }
        }
    }

    // epilogue: C layout col=lane&31 (pixel), row=(reg&3)+8*(reg>>2)+4*ah (co)
    float* ob = out + (size_t)n * COUT * HW;
    #pragma unroll
    for (int ct = 0; ct < 2; ct++) {
        #pragma unroll
        for (int reg = 0; reg < 16; reg++) {
            int co = cobase + ct * 32 + (reg & 3) + ((reg >> 2) << 3) + (ah << 2);
            float bv = bias[co];
            #pragma unroll
            for (int pt = 0; pt < 4; pt++) {
                int p = pxbase + pt * 32 + al;
                int off = (h0 + (p >> 4)) * Wdim + w0 + (p & 15);
                ob[(size_t)co * HW + off] = (float)acc[ct][pt][reg] + bv;
            }
        }
    }
}

extern "C" void kernel_launch(void* const* d_in, const int* in_sizes, int n_in,
                              void* d_out, int out_size, void* d_ws, size_t ws_size,
                              hipStream_t stream) {
    const float* x = (const float*)d_in[0];
    const float* W = (const float*)d_in[1];
    const float* b = (const float*)d_in[2];
    float* out = (float*)d_out;
    char* ws = (char*)d_ws;
    char*  Wi8 = ws;
    uint4* pkx = (uint4*)(ws + 147456);

    pack_w_i8<<<dim3((COUT * 9 + 255) / 256), dim3(256), 0, stream>>>(W, Wi8);
    pack_x_kernel<<<dim3(NB * HW / 4 / 256), dim3(256), 0, stream>>>(x, pkx);
    binconv_mfma<<<dim3(7, 7, NB), dim3(256), 0, stream>>>(pkx, Wi8, b, out);
}

// Round 13
// 142.443 us; speedup vs baseline: 1.5622x; 1.1349x over previous
//
#include <hip/hip_runtime.h>
#include <stdint.h>

#define Hdim 112
#define Wdim 112
#define CIN  128
#define COUT 128
#define NB   32
#define HW   (Hdim*Wdim)   // 12544

// ws layout:
//   Wi8 : int8 [9][COUT][CIN]  @ 0        (147456 B)  weight signs as +-1
//   pkx : uint4[NB*HW]         @ 147456   (6.4 MB)    packed activation sign bits

typedef int   v4i __attribute__((ext_vector_type(4)));
typedef int  v16i __attribute__((ext_vector_type(16)));
typedef float v4f __attribute__((ext_vector_type(4)));

__global__ void pack_w_i8(const float* __restrict__ W, char* __restrict__ Wi8) {
    int t = blockIdx.x * blockDim.x + threadIdx.x;
    if (t >= COUT * 9) return;
    int co = t / 9, tap = t % 9;
    const float* wp = W + (size_t)co * CIN * 9 + tap;
    uint32_t* dst = (uint32_t*)(Wi8 + ((size_t)tap * COUT + co) * CIN);
    #pragma unroll
    for (int c4 = 0; c4 < 32; c4++) {
        uint32_t word = 0;
        #pragma unroll
        for (int j = 0; j < 4; j++) {
            uint32_t neg = __float_as_uint(wp[(size_t)(c4 * 4 + j) * 9]) >> 31;
            word |= (neg ? 0xFFu : 0x01u) << (8 * j);
        }
        dst[c4] = word;
    }
}

// each thread packs 4 consecutive pixels across all 128 channels.
// x is 205 MB single-use -> nontemporal loads keep it out of L2/L3.
__global__ __launch_bounds__(256) void pack_x_kernel(const float* __restrict__ x,
                                                     uint4* __restrict__ pkx) {
    int gid = blockIdx.x * blockDim.x + threadIdx.x;   // 0..100351
    int n = gid / (HW / 4);
    int p = (gid - n * (HW / 4)) * 4;
    const float* xp = x + (size_t)n * CIN * HW + p;
    uint32_t m[4][4] = {{0,0,0,0},{0,0,0,0},{0,0,0,0},{0,0,0,0}};
    #pragma unroll
    for (int c = 0; c < CIN; c++) {
        v4f v = __builtin_nontemporal_load(
            reinterpret_cast<const v4f*>(xp + (size_t)c * HW));
        int q = c >> 5, s = c & 31;
        m[0][q] |= (__float_as_uint(v.x) >> 31) << s;
        m[1][q] |= (__float_as_uint(v.y) >> 31) << s;
        m[2][q] |= (__float_as_uint(v.z) >> 31) << s;
        m[3][q] |= (__float_as_uint(v.w) >> 31) << s;
    }
    uint4* op = pkx + (size_t)n * HW + p;
    #pragma unroll
    for (int j = 0; j < 4; j++)
        op[j] = make_uint4(m[j][0], m[j][1], m[j][2], m[j][3]);
}

// spread low 4 bits into 4 bytes: bit=0 -> 0x01 (+1), bit=1 -> 0xFF (-1)
__device__ __forceinline__ uint32_t expand4(uint32_t b) {
    uint32_t s = ((b & 0xFu) * 0x00204081u) & 0x01010101u;
    return 0x01010101u ^ (s * 0xFEu);
}

// implicit-GEMM binconv via i8 MFMA (R11 structure + NONTEMPORAL stores).
// R9/R10 PMC: FETCH_SIZE 42-44 MB/dispatch — the 205 MB output store
// stream thrashes L2 (25 MB/XCD through 4 MB) AND L3 (~205 MB vs 256 MB),
// evicting the 147 KB weight panel, so the tap-boundary vmcnt(0) on the
// A-prefetch ate HBM-class (~900cy) latency; both resident waves stalled
// in lockstep (MfmaUtil 19%). nt stores bypass cache allocation and keep
// Wi8/pkx resident.
__global__ __launch_bounds__(256, 2) void binconv_mfma(
    const uint4* __restrict__ pkx, const char* __restrict__ Wi8,
    const float* __restrict__ bias, float* __restrict__ out) {
    __shared__ uint4 halo4[8 * 324];        // 8 slots * 324 px * 16B = 41472 B
    char* halo = (char*)halo4;

    int tid = threadIdx.x;
    int w0 = blockIdx.x * 16;
    int h0 = blockIdx.y * 16;
    int n  = blockIdx.z;

    // stage 18x18 halo: expand 128 sign bits -> 128 i8 (+-1, 0 if OOB)
    for (int i = tid; i < 324; i += 256) {
        int r = i / 18, c = i - r * 18;
        int h = h0 - 1 + r, w = w0 - 1 + c;
        bool valid = (h >= 0) && (h < Hdim) && (w >= 0) && (w < Wdim);
        uint32_t keep = valid ? 0xFFFFFFFFu : 0u;
        uint4 bits = make_uint4(0u, 0u, 0u, 0u);
        if (valid) bits = pkx[(size_t)n * HW + h * Wdim + w];
        uint32_t src[4] = {bits.x, bits.y, bits.z, bits.w};
        #pragma unroll
        for (int s = 0; s < 8; s++) {       // slot s = ci 16s..16s+15
            uint32_t q = src[s >> 1] >> ((s & 1) * 16);
            uint4 ov;
            ov.x = expand4(q)       & keep;
            ov.y = expand4(q >> 4)  & keep;
            ov.z = expand4(q >> 8)  & keep;
            ov.w = expand4(q >> 12) & keep;
            *reinterpret_cast<uint4*>(&halo[s * 5184 + i * 16]) = ov;
        }
    }

    int wid = tid >> 6, l = tid & 63;
    int al = l & 31, ah = l >> 5;
    int cobase = (wid & 1) * 64;            // wave's 64-co half
    int pxbase = (wid >> 1) * 128;          // wave's 128-px half

    // per-px-tile halo byte base at tap (0,0)
    int pib[4];
    #pragma unroll
    for (int pt = 0; pt < 4; pt++) {
        int p = pxbase + pt * 32 + al;
        pib[pt] = ((p >> 4) * 18 + (p & 15)) * 16;
    }

    const char* wA = Wi8 + ((size_t)cobase + al) * CIN + ah * 16;

    // A fragments for tap 0 (ct=0: co+0, ct=1: co+32)
    v4i A[2][4];
    #pragma unroll
    for (int kk = 0; kk < 4; kk++) {
        A[0][kk] = *reinterpret_cast<const v4i*>(wA + kk * 32);
        A[1][kk] = *reinterpret_cast<const v4i*>(wA + 32 * CIN + kk * 32);
    }

    v16i acc[2][4];
    #pragma unroll
    for (int ct = 0; ct < 2; ct++)
        #pragma unroll
        for (int pt = 0; pt < 4; pt++)
            #pragma unroll
            for (int i = 0; i < 16; i++) acc[ct][pt][i] = 0;

    __syncthreads();

    #pragma unroll
    for (int tap = 0; tap < 9; tap++) {
        // prefetch next tap's A while this tap's MFMAs run
        v4i N[2][4];
        if (tap < 8) {
            const char* wt = wA + (size_t)(tap + 1) * COUT * CIN;
            #pragma unroll
            for (int kk = 0; kk < 4; kk++) {
                N[0][kk] = *reinterpret_cast<const v4i*>(wt + kk * 32);
                N[1][kk] = *reinterpret_cast<const v4i*>(wt + 32 * CIN + kk * 32);
            }
        }
        int doff = ((tap / 3) * 18 + (tap % 3)) * 16;
        #pragma unroll
        for (int kk = 0; kk < 4; kk++) {
            int sb = (kk * 2 + ah) * 5184 + doff;
            v4i b[4];
            #pragma unroll
            for (int pt = 0; pt < 4; pt++)
                b[pt] = *reinterpret_cast<const v4i*>(&halo[sb + pib[pt]]);
            #pragma unroll
            for (int pt = 0; pt < 4; pt++) {
                acc[0][pt] = __builtin_amdgcn_mfma_i32_32x32x32_i8(A[0][kk], b[pt], acc[0][pt], 0, 0, 0);
                acc[1][pt] = __builtin_amdgcn_mfma_i32_32x32x32_i8(A[1][kk], b[pt], acc[1][pt], 0, 0, 0);
            }
        }
        if (tap < 8) {
            #pragma unroll
            for (int kk = 0; kk < 4; kk++) { A[0][kk] = N[0][kk]; A[1][kk] = N[1][kk]; }
        }
    }

    // epilogue: C layout col=lane&31 (pixel), row=(reg&3)+8*(reg>>2)+4*ah (co)
    // NONTEMPORAL stores: no cache allocation -> stops evicting Wi8/pkx.
    float* ob = out + (size_t)n * COUT * HW;
    #pragma unroll
    for (int ct = 0; ct < 2; ct++) {
        #pragma unroll
        for (int reg = 0; reg < 16; reg++) {
            int co = cobase + ct * 32 + (reg & 3) + ((reg >> 2) << 3) + (ah << 2);
            float bv = bias[co];
            #pragma unroll
            for (int pt = 0; pt < 4; pt++) {
                int p = pxbase + pt * 32 + al;
                int off = (h0 + (p >> 4)) * Wdim + w0 + (p & 15);
                __builtin_nontemporal_store((float)acc[ct][pt][reg] + bv,
                                            &ob[(size_t)co * HW + off]);
            }
        }
    }
}

extern "C" void kernel_launch(void* const* d_in, const int* in_sizes, int n_in,
                              void* d_out, int out_size, void* d_ws, size_t ws_size,
                              hipStream_t stream) {
    const float* x = (const float*)d_in[0];
    const float* W = (const float*)d_in[1];
    const float* b = (const float*)d_in[2];
    float* out = (float*)d_out;
    char* ws = (char*)d_ws;
    char*  Wi8 = ws;
    uint4* pkx = (uint4*)(ws + 147456);

    pack_w_i8<<<dim3((COUT * 9 + 255) / 256), dim3(256), 0, stream>>>(W, Wi8);
    pack_x_kernel<<<dim3(NB * HW / 4 / 256), dim3(256), 0, stream>>>(x, pkx);
    binconv_mfma<<<dim3(7, 7, NB), dim3(256), 0, stream>>>(pkx, Wi8, b, out);
}

// Round 14
// 126.915 us; speedup vs baseline: 1.7533x; 1.1224x over previous
//
#include <hip/hip_runtime.h>
#include <stdint.h>

#define Hdim 112
#define Wdim 112
#define CIN  128
#define COUT 128
#define NB   32
#define HW   (Hdim*Wdim)   // 12544
#define HALO_W 114
#define HALO_PX (4*HALO_W)         // 456 pixels (4 rows x 114 cols)
#define SLOT_STRIDE (HALO_PX*16)   // 7296 B per ci-16 slot

// ws layout:
//   Wi8 : int8 [9][COUT][CIN]  @ 0        (147456 B)  weight signs as +-1
//   pkx : uint4[NB*HW]         @ 147456   (6.4 MB)    packed activation sign bits

typedef int   v4i __attribute__((ext_vector_type(4)));
typedef int  v16i __attribute__((ext_vector_type(16)));
typedef float v4f __attribute__((ext_vector_type(4)));

__global__ void pack_w_i8(const float* __restrict__ W, char* __restrict__ Wi8) {
    int t = blockIdx.x * blockDim.x + threadIdx.x;
    if (t >= COUT * 9) return;
    int co = t / 9, tap = t % 9;
    const float* wp = W + (size_t)co * CIN * 9 + tap;
    uint32_t* dst = (uint32_t*)(Wi8 + ((size_t)tap * COUT + co) * CIN);
    #pragma unroll
    for (int c4 = 0; c4 < 32; c4++) {
        uint32_t word = 0;
        #pragma unroll
        for (int j = 0; j < 4; j++) {
            uint32_t neg = __float_as_uint(wp[(size_t)(c4 * 4 + j) * 9]) >> 31;
            word |= (neg ? 0xFFu : 0x01u) << (8 * j);
        }
        dst[c4] = word;
    }
}

// each thread packs 4 consecutive pixels across all 128 channels.
// x is 205 MB single-use -> nontemporal loads keep it out of L2/L3.
__global__ __launch_bounds__(256) void pack_x_kernel(const float* __restrict__ x,
                                                     uint4* __restrict__ pkx) {
    int gid = blockIdx.x * blockDim.x + threadIdx.x;   // 0..100351
    int n = gid / (HW / 4);
    int p = (gid - n * (HW / 4)) * 4;
    const float* xp = x + (size_t)n * CIN * HW + p;
    uint32_t m[4][4] = {{0,0,0,0},{0,0,0,0},{0,0,0,0},{0,0,0,0}};
    #pragma unroll
    for (int c = 0; c < CIN; c++) {
        v4f v = __builtin_nontemporal_load(
            reinterpret_cast<const v4f*>(xp + (size_t)c * HW));
        int q = c >> 5, s = c & 31;
        m[0][q] |= (__float_as_uint(v.x) >> 31) << s;
        m[1][q] |= (__float_as_uint(v.y) >> 31) << s;
        m[2][q] |= (__float_as_uint(v.z) >> 31) << s;
        m[3][q] |= (__float_as_uint(v.w) >> 31) << s;
    }
    uint4* op = pkx + (size_t)n * HW + p;
    #pragma unroll
    for (int j = 0; j < 4; j++)
        op[j] = make_uint4(m[j][0], m[j][1], m[j][2], m[j][3]);
}

// spread low 4 bits into 4 bytes: bit=0 -> 0x01 (+1), bit=1 -> 0xFF (-1)
__device__ __forceinline__ uint32_t expand4(uint32_t b) {
    uint32_t s = ((b & 0xFu) * 0x00204081u) & 0x01010101u;
    return 0x01010101u ^ (s * 0xFEu);
}

// implicit-GEMM binconv via i8 MFMA — FULL-WIDTH ROW TILES.
// R1-R13 invariant: every variant plateaued 115-147us writing 205 MB as
// scattered 64B segments (16-wide tiles, 448B row stride, 50KB plane
// stride) — HBM write efficiency ~27% => ~120us wall. This block covers
// 2 FULL rows (112w) x 128co: per (n,co) it writes 224 consecutive
// floats (896B runs) -> streaming writes.
// Wave = 32co x 224px: acc = 7 x v16i = 112 AGPR. Halo 4x114 px
// expanded i8 in LDS [slot][pixel][16B]: ds_read addr = reg + const imm
// (max 47456 < 64K), conflict-free. Weights per-tap prefetch (R8).
// OOB pixels masked AFTER expand -> exact zero padding (absmax 0.0).
__global__ __launch_bounds__(256, 2) void binconv_mfma(
    const uint4* __restrict__ pkx, const char* __restrict__ Wi8,
    const float* __restrict__ bias, float* __restrict__ out) {
    __shared__ char halo[8 * SLOT_STRIDE];   // 58368 B

    int tid = threadIdx.x;
    int hy = blockIdx.x;                     // row-pair 0..55
    int n  = blockIdx.y;
    int h0 = hy * 2;

    // stage 4x114 halo: expand 128 sign bits -> 128 i8 (+-1, 0 if OOB)
    for (int i = tid; i < HALO_PX; i += 256) {
        int r = i / HALO_W, c = i - r * HALO_W;
        int h = h0 - 1 + r, w = c - 1;
        bool valid = (h >= 0) && (h < Hdim) && (w >= 0) && (w < Wdim);
        uint32_t keep = valid ? 0xFFFFFFFFu : 0u;
        int hc = min(max(h, 0), Hdim - 1);
        int wc = min(max(w, 0), Wdim - 1);
        uint4 bits = pkx[(size_t)n * HW + hc * Wdim + wc];   // always in-bounds
        uint32_t src[4] = {bits.x, bits.y, bits.z, bits.w};
        #pragma unroll
        for (int s = 0; s < 8; s++) {        // slot s = ci 16s..16s+15
            uint32_t q = src[s >> 1] >> ((s & 1) * 16);
            uint4 ov;
            ov.x = expand4(q)       & keep;
            ov.y = expand4(q >> 4)  & keep;
            ov.z = expand4(q >> 8)  & keep;
            ov.w = expand4(q >> 12) & keep;
            *reinterpret_cast<uint4*>(&halo[s * SLOT_STRIDE + i * 16]) = ov;
        }
    }

    int wid = tid >> 6, l = tid & 63;
    int al = l & 31, ah = l >> 5;
    int cobase = wid * 32;                   // wave's 32-co slice

    // per-pt halo byte base at tap (0,0): pixel P = pt*32+al of 2x112 tile
    int hb[7];
    #pragma unroll
    for (int pt = 0; pt < 7; pt++) {
        int P = pt * 32 + al;
        int r = (P >= Wdim) ? 1 : 0;
        int w = P - r * Wdim;
        hb[pt] = (r * HALO_W + w) * 16 + ah * SLOT_STRIDE;
    }

    const char* wA = Wi8 + ((size_t)cobase + al) * CIN + ah * 16;

    v16i acc[7];
    #pragma unroll
    for (int pt = 0; pt < 7; pt++)
        #pragma unroll
        for (int i = 0; i < 16; i++) acc[pt][i] = 0;

    // A fragments for tap 0
    v4i A[4];
    #pragma unroll
    for (int kk = 0; kk < 4; kk++)
        A[kk] = *reinterpret_cast<const v4i*>(wA + kk * 32);

    __syncthreads();

    #pragma unroll
    for (int tap = 0; tap < 9; tap++) {
        // prefetch next tap's A while this tap's MFMAs run
        v4i N[4];
        if (tap < 8) {
            const char* wt = wA + (size_t)(tap + 1) * COUT * CIN;
            #pragma unroll
            for (int kk = 0; kk < 4; kk++)
                N[kk] = *reinterpret_cast<const v4i*>(wt + kk * 32);
        }
        const int dy = tap / 3, dx = tap % 3;
        const int imm = (dy * HALO_W + dx) * 16;   // constant per tap
        #pragma unroll
        for (int kk = 0; kk < 4; kk++) {
            const int simm = imm + kk * 2 * SLOT_STRIDE;   // + ah via hb[]
            v4i b[7];
            #pragma unroll
            for (int pt = 0; pt < 7; pt++)
                b[pt] = *reinterpret_cast<const v4i*>(&halo[hb[pt] + simm]);
            #pragma unroll
            for (int pt = 0; pt < 7; pt++)
                acc[pt] = __builtin_amdgcn_mfma_i32_32x32x32_i8(A[kk], b[pt], acc[pt], 0, 0, 0);
        }
        if (tap < 8) {
            #pragma unroll
            for (int kk = 0; kk < 4; kk++) A[kk] = N[kk];
        }
    }

    // epilogue: C col=lane&31 (pixel), row=(reg&3)+8*(reg>>2)+4*ah (co).
    // Writes: per (co): 7 x 128B segments forming 896B contiguous runs.
    float* ob = out + (size_t)n * COUT * HW + (size_t)h0 * Wdim;
    #pragma unroll
    for (int reg = 0; reg < 16; reg++) {
        int co = cobase + (reg & 3) + ((reg >> 2) << 3) + (ah << 2);
        float bv = bias[co];
        float* op = ob + (size_t)co * HW + al;
        #pragma unroll
        for (int pt = 0; pt < 7; pt++)
            __builtin_nontemporal_store((float)acc[pt][reg] + bv, op + pt * 32);
    }
}

extern "C" void kernel_launch(void* const* d_in, const int* in_sizes, int n_in,
                              void* d_out, int out_size, void* d_ws, size_t ws_size,
                              hipStream_t stream) {
    const float* x = (const float*)d_in[0];
    const float* W = (const float*)d_in[1];
    const float* b = (const float*)d_in[2];
    float* out = (float*)d_out;
    char* ws = (char*)d_ws;
    char*  Wi8 = ws;
    uint4* pkx = (uint4*)(ws + 147456);

    pack_w_i8<<<dim3((COUT * 9 + 255) / 256), dim3(256), 0, stream>>>(W, Wi8);
    pack_x_kernel<<<dim3(NB * HW / 4 / 256), dim3(256), 0, stream>>>(x, pkx);
    binconv_mfma<<<dim3(Hdim / 2, NB), dim3(256), 0, stream>>>(pkx, Wi8, b, out);
}